// Round 2
// baseline (2040.486 us; speedup 1.0000x reference)
//
#include <hip/hip_runtime.h>

#define NN 16384
#define DIN 128
#define DH 64
#define NC 16

// ws float-offset layout (first 20480 floats), then byte-offset buffers
#define OFF_G   0        // 128*16
#define OFF_C1  2048
#define OFF_C2  2064
#define OFF_C3  2080
#define OFF_C4  2096
#define OFF_T1  4096     // 128*64
#define OFF_T2  12288    // 128*64

#define ZTA_BYTE 81920                            // bf16 z, transposed [16][NN]
#define ZTB_BYTE (ZTA_BYTE + NN*NC*2)             // 606208
#define ADJQ_BYTE (ZTB_BYTE + NN*NC*2)            // 1130496 (16B aligned)
#define WS_NEED_Q ((size_t)ADJQ_BYTE + (size_t)NN*(size_t)NN)

#define QSCALE 4177920.0f        // 255 * NN
#define DSCALE (1.0f/4177920.0f)

typedef __attribute__((ext_vector_type(8))) short bf16x8;
typedef __attribute__((ext_vector_type(4))) float f32x4;

__device__ __forceinline__ unsigned int f2bf(float f) {
  unsigned int u = __builtin_bit_cast(unsigned int, f);
  u += 0x7fffu + ((u >> 16) & 1u);   // RNE to bf16
  return u >> 16;
}

// 8 q8 bytes (k-consecutive) -> bf16x8 A-fragment. ints 0..255 exact in bf16.
__device__ __forceinline__ bf16x8 q8x8_to_bf16(uint2 q) {
  bf16x8 r;
  #pragma unroll
  for (int i = 0; i < 4; ++i) {
    float f0 = (float)((q.x >> (8 * i)) & 0xffu);   // v_cvt_f32_ubyte{i}
    float f1 = (float)((q.y >> (8 * i)) & 0xffu);
    r[i]     = (short)(__builtin_bit_cast(unsigned int, f0) >> 16);
    r[4 + i] = (short)(__builtin_bit_cast(unsigned int, f1) >> 16);
  }
  return r;
}

__device__ __forceinline__ bf16x8 f32x8_to_bf16(f32x4 a, f32x4 b) {
  bf16x8 r;
  #pragma unroll
  for (int i = 0; i < 4; ++i) {
    r[i]     = (short)f2bf(a[i]);
    r[4 + i] = (short)f2bf(b[i]);
  }
  return r;
}

__device__ __forceinline__ unsigned int quant4(f32x4 v) {
  unsigned int b0 = __float2uint_rn(v[0] * QSCALE);
  unsigned int b1 = __float2uint_rn(v[1] * QSCALE);
  unsigned int b2 = __float2uint_rn(v[2] * QSCALE);
  unsigned int b3 = __float2uint_rn(v[3] * QSCALE);
  return b0 | (b1 << 8) | (b2 << 16) | (b3 << 24);
}

// ---------------- prep: collapse weights ----------------
// G = Win@Wh0@Wh1@Wout [128x16]; c1=bin@Wh0@Wh1@Wout; c2=bh0@Wh1@Wout; c3=bh1@Wout; c4=bout
__global__ __launch_bounds__(256) void prep_kernel(
    const float* __restrict__ Win, const float* __restrict__ bin,
    const float* __restrict__ Wh,  const float* __restrict__ bh,
    const float* __restrict__ Wout,const float* __restrict__ bout,
    float* __restrict__ ws)
{
  const int t = threadIdx.x;
  const float* Wh0 = Wh;
  const float* Wh1 = Wh + DH*DH;
  float* T1 = ws + OFF_T1;
  float* T2 = ws + OFF_T2;
  float* G  = ws + OFF_G;

  for (int o = t; o < DIN*DH; o += 256) {
    int r = o >> 6, c = o & 63;
    float s = 0.f;
    for (int k = 0; k < DH; ++k) s += Win[r*DH + k] * Wh0[k*DH + c];
    T1[o] = s;
  }
  __syncthreads();
  for (int o = t; o < DIN*DH; o += 256) {
    int r = o >> 6, c = o & 63;
    float s = 0.f;
    for (int k = 0; k < DH; ++k) s += T1[r*DH + k] * Wh1[k*DH + c];
    T2[o] = s;
  }
  __syncthreads();
  for (int o = t; o < DIN*NC; o += 256) {
    int r = o >> 4, c = o & 15;
    float s = 0.f;
    for (int k = 0; k < DH; ++k) s += T2[r*DH + k] * Wout[k*NC + c];
    G[o] = s;
  }
  __shared__ float u1[DH], u2[DH], u1b[DH];
  if (t < DH) {
    float s1 = 0.f, s2 = 0.f;
    for (int k = 0; k < DH; ++k) { s1 += bin[k]*Wh0[k*DH + t]; s2 += bh[k]*Wh1[k*DH + t]; }
    u1[t] = s1; u2[t] = s2;
  }
  __syncthreads();
  if (t < DH) {
    float s = 0.f;
    for (int k = 0; k < DH; ++k) s += u1[k]*Wh1[k*DH + t];
    u1b[t] = s;
  }
  __syncthreads();
  if (t < NC) {
    float s1 = 0.f, s2 = 0.f, s3 = 0.f;
    for (int k = 0; k < DH; ++k) {
      s1 += u1b[k]   * Wout[k*NC + t];
      s2 += u2[k]    * Wout[k*NC + t];
      s3 += bh[DH+k] * Wout[k*NC + t];
    }
    ws[OFF_C1 + t] = s1;
    ws[OFF_C2 + t] = s2;
    ws[OFF_C3 + t] = s3;
    ws[OFF_C4 + t] = bout[t];
  }
}

// ---------------- z0 = x @ G, written bf16 transposed [16][NN] ----------------
__global__ __launch_bounds__(256) void z0_kernel(const float* __restrict__ x,
    const float* __restrict__ ws, unsigned short* __restrict__ zT)
{
  __shared__ float Gs[DIN*NC];
  for (int i = threadIdx.x; i < DIN*NC; i += 256) Gs[i] = ws[OFF_G + i];
  __syncthreads();
  const int r = threadIdx.x >> 4, c = threadIdx.x & 15;
  const int row = blockIdx.x * 16 + r;
  const float* xr = x + (size_t)row * DIN;
  float s = 0.f;
  #pragma unroll
  for (int k = 0; k < DIN; ++k) s += xr[k] * Gs[k*NC + c];
  zT[(size_t)c * NN + row] = (unsigned short)f2bf(s);
}

// ---------------- adj pass: zout = adj @ zin + cvec ----------------
// Barrier-free K-loop: A and B fragments loaded straight from global.
// Each block = 16 output rows; 4 waves K-split NN/4 each; LDS only for the
// final partial-sum combine.
// MODE 0: fp32 adj in, bf16-zT out               (fallback mid pass)
// MODE 1: fp32 adj in, write q8 adj, bf16-zT out (main pass 1)
// MODE 2: q8 adj in, bf16-zT out                 (main mid passes)
// MODE 3: q8 adj in, fp32 final out              (main last pass)
// MODE 4: fp32 adj in, fp32 final out            (fallback last pass)
template<int MODE>
__global__ __launch_bounds__(256) void gcn_pass(
    const float* __restrict__ adjf,
    const unsigned char* __restrict__ adjq,
    unsigned char* __restrict__ adjq_out,
    const unsigned short* __restrict__ zT_in,
    unsigned short* __restrict__ zT_out,
    float* __restrict__ fout,
    const float* __restrict__ cvec)
{
  constexpr bool QIN  = (MODE == 2 || MODE == 3);
  constexpr bool FOUT = (MODE == 3 || MODE == 4);
  constexpr int KW = NN / 4;               // K-range per wave

  __shared__ __align__(16) float epi[3 * 256];

  const int t = threadIdx.x;
  const int wave = t >> 6;
  const int lane = t & 63;
  const int i0 = blockIdx.x * 16;          // 16 output rows per block
  const int m = lane & 15;                 // A row (strip-local) == B col
  const int quad = lane >> 4;
  const int kw0 = wave * KW;

  f32x4 acc = {0.f, 0.f, 0.f, 0.f};
  const unsigned short* zrow = zT_in + (size_t)m * NN + kw0 + quad * 8;

  if constexpr (QIN) {
    const unsigned char* arow = adjq + (size_t)(i0 + m) * NN + kw0 + quad * 8;
    #pragma unroll 8
    for (int kk = 0; kk < KW; kk += 32) {
      uint2 q = *(const uint2*)(arow + kk);
      bf16x8 bv = *(const bf16x8*)(zrow + kk);
      bf16x8 av = q8x8_to_bf16(q);
      acc = __builtin_amdgcn_mfma_f32_16x16x32_bf16(av, bv, acc, 0, 0, 0);
    }
  } else {
    const float* arow = adjf + (size_t)(i0 + m) * NN + kw0 + quad * 8;
    unsigned char* qrow = (MODE == 1)
        ? adjq_out + (size_t)(i0 + m) * NN + kw0 + quad * 8 : nullptr;
    #pragma unroll 4
    for (int kk = 0; kk < KW; kk += 32) {
      f32x4 a0 = __builtin_nontemporal_load((const f32x4*)(arow + kk));
      f32x4 a1 = __builtin_nontemporal_load((const f32x4*)(arow + kk) + 1);
      bf16x8 bv = *(const bf16x8*)(zrow + kk);
      bf16x8 av = f32x8_to_bf16(a0, a1);
      if constexpr (MODE == 1) {
        uint2 qw;
        qw.x = quant4(a0);
        qw.y = quant4(a1);
        *(uint2*)(qrow + kk) = qw;
      }
      acc = __builtin_amdgcn_mfma_f32_16x16x32_bf16(av, bv, acc, 0, 0, 0);
    }
  }

  // ---- epilogue: combine 4 K-partials, scale, bias, store
  // D layout: col = lane&15 (= z-col m), row = quad*4 + reg (strip-local adj row)
  if (wave != 0) {
    #pragma unroll
    for (int rg = 0; rg < 4; ++rg) {
      int row = quad * 4 + rg;
      epi[(wave - 1) * 256 + row * 16 + m] = acc[rg];
    }
  }
  __syncthreads();
  if (wave == 0) {
    const float scale = QIN ? DSCALE : 1.0f;
    const float cv = cvec[m];
    float vals[4];
    #pragma unroll
    for (int rg = 0; rg < 4; ++rg) {
      int row = quad * 4 + rg;
      float s = acc[rg] + epi[row*16 + m] + epi[256 + row*16 + m] + epi[512 + row*16 + m];
      vals[rg] = s * scale + cv;
    }
    if constexpr (FOUT) {
      #pragma unroll
      for (int rg = 0; rg < 4; ++rg)
        fout[(size_t)(i0 + quad*4 + rg) * NC + m] = vals[rg];
    } else {
      unsigned int lo = f2bf(vals[0]) | (f2bf(vals[1]) << 16);
      unsigned int hi = f2bf(vals[2]) | (f2bf(vals[3]) << 16);
      *(uint2*)(zT_out + (size_t)m * NN + i0 + quad*4) = make_uint2(lo, hi);
    }
  }
}

extern "C" void kernel_launch(void* const* d_in, const int* in_sizes, int n_in,
                              void* d_out, int out_size, void* d_ws, size_t ws_size,
                              hipStream_t stream) {
  const float* x    = (const float*)d_in[0];
  const float* adj  = (const float*)d_in[1];
  const float* Win  = (const float*)d_in[2];
  const float* bin  = (const float*)d_in[3];
  const float* Wh   = (const float*)d_in[4];
  const float* bh   = (const float*)d_in[5];
  const float* Wout = (const float*)d_in[6];
  const float* bout = (const float*)d_in[7];
  float* wsf = (float*)d_ws;
  char*  wsb = (char*)d_ws;
  unsigned short* zTA = (unsigned short*)(wsb + ZTA_BYTE);
  unsigned short* zTB = (unsigned short*)(wsb + ZTB_BYTE);
  unsigned char*  adjqp = (unsigned char*)(wsb + ADJQ_BYTE);
  float* out = (float*)d_out;
  const float* c1 = wsf + OFF_C1;
  const float* c2 = wsf + OFF_C2;
  const float* c3 = wsf + OFF_C3;
  const float* c4 = wsf + OFF_C4;

  prep_kernel<<<1, 256, 0, stream>>>(Win, bin, Wh, bh, Wout, bout, wsf);
  z0_kernel<<<NN/16, 256, 0, stream>>>(x, wsf, zTA);

  if (ws_size >= WS_NEED_Q) {
    gcn_pass<1><<<NN/16, 256, 0, stream>>>(adj, nullptr, adjqp, zTA, zTB, nullptr, c1);
    gcn_pass<2><<<NN/16, 256, 0, stream>>>(nullptr, adjqp, nullptr, zTB, zTA, nullptr, c2);
    gcn_pass<2><<<NN/16, 256, 0, stream>>>(nullptr, adjqp, nullptr, zTA, zTB, nullptr, c3);
    gcn_pass<3><<<NN/16, 256, 0, stream>>>(nullptr, adjqp, nullptr, zTB, nullptr, out, c4);
  } else {
    gcn_pass<0><<<NN/16, 256, 0, stream>>>(adj, nullptr, nullptr, zTA, zTB, nullptr, c1);
    gcn_pass<0><<<NN/16, 256, 0, stream>>>(adj, nullptr, nullptr, zTB, zTA, nullptr, c2);
    gcn_pass<0><<<NN/16, 256, 0, stream>>>(adj, nullptr, nullptr, zTA, zTB, nullptr, c3);
    gcn_pass<4><<<NN/16, 256, 0, stream>>>(adj, nullptr, nullptr, zTB, nullptr, out, c4);
  }
}